// Round 1
// baseline (84.425 us; speedup 1.0000x reference)
//
#include <hip/hip_runtime.h>
#include <cstdint>
#include <cstddef>

#define NB 20000
#define NT 1000
#define P_PAIRS 50000
#define MARGIN 2.0f
#define RANK_W 0.3f
#define NEG_SENT -1e9f

// ---------------- workspace layout (bytes) ----------------
// [0,          2560000)  label bitmask: uint32 [NB][32]
// [2560000,    2560004)  float  ranking_sum accumulator
// [2560004,    2560008)  uint   num_ranking_pairs accumulator
// [2560016,    2640016)  float  sq_partials[NB]        (one per row, no zero-init needed)
// [2640016,    3040016)  float  top5[NB][5]
// [3040016,    3120016)  int    numneg[NB]
// memset range: [0, 2560016)  (bitmask + accumulators)

__global__ void scatter_labels_kernel(const int* __restrict__ pb,
                                      const int* __restrict__ pt,
                                      unsigned int* __restrict__ mask) {
    int p = blockIdx.x * blockDim.x + threadIdx.x;
    if (p >= P_PAIRS) return;
    int b = pb[p];
    int t = pt[p];
    atomicOr(&mask[b * 32 + (t >> 5)], 1u << (t & 31));
}

// One wave (64 lanes) per row. 4 waves / block.
__global__ void row_kernel(const float* __restrict__ scores,
                           const unsigned int* __restrict__ mask,
                           float* __restrict__ sq_partials,
                           float* __restrict__ top5,
                           int* __restrict__ numneg) {
    const int wave = threadIdx.x >> 6;
    const int lane = threadIdx.x & 63;
    const int row  = blockIdx.x * 4 + wave;
    if (row >= NB) return;

    const float4* rowp = reinterpret_cast<const float4*>(scores + (size_t)row * NT);
    const unsigned int* mrow = mask + row * 32;

    float t0 = NEG_SENT, t1 = NEG_SENT, t2 = NEG_SENT, t3 = NEG_SENT, t4 = NEG_SENT;
    float sq = 0.0f;
    int pcount = 0;

    for (int i = lane; i < NT / 4; i += 64) {
        float4 v = rowp[i];
        int e = i * 4;
        unsigned int bits = (mrow[e >> 5] >> (e & 31)) & 0xFu;
        float vv[4] = {v.x, v.y, v.z, v.w};
        #pragma unroll
        for (int j = 0; j < 4; ++j) {
            float x = vv[j];
            float s = 1.0f / (1.0f + __expf(-x));
            int lab = (bits >> j) & 1;
            float d = (float)lab - s;
            sq += d * d;
            if (lab) {
                pcount++;
            } else if (x > t4) {
                if (x > t0)      { t4 = t3; t3 = t2; t2 = t1; t1 = t0; t0 = x; }
                else if (x > t1) { t4 = t3; t3 = t2; t2 = t1; t1 = x; }
                else if (x > t2) { t4 = t3; t3 = t2; t2 = x; }
                else if (x > t3) { t4 = t3; t3 = x; }
                else             { t4 = x; }
            }
        }
    }

    // wave-reduce sq sum and positive count
    #pragma unroll
    for (int off = 32; off >= 1; off >>= 1) {
        sq     += __shfl_xor(sq, off);
        pcount += __shfl_xor(pcount, off);
    }

    // wave-merge top-5: 5 rounds of argmax + pop (lowest tied lane pops)
    float t[5] = {t0, t1, t2, t3, t4};
    float r[5];
    #pragma unroll
    for (int k = 0; k < 5; ++k) {
        float v = t[0];
        float m = v;
        #pragma unroll
        for (int off = 32; off >= 1; off >>= 1) m = fmaxf(m, __shfl_xor(m, off));
        unsigned long long ball = __ballot(v == m);
        int owner = __ffsll(ball) - 1;
        if (lane == owner) { t[0] = t[1]; t[1] = t[2]; t[2] = t[3]; t[3] = t[4]; t[4] = NEG_SENT; }
        r[k] = m;
    }

    if (lane == 0) {
        sq_partials[row] = sq;
        #pragma unroll
        for (int k = 0; k < 5; ++k) top5[row * 5 + k] = r[k];
        numneg[row] = NT - pcount;
    }
}

__global__ void pair_kernel(const float* __restrict__ scores,
                            const int* __restrict__ pb,
                            const int* __restrict__ pt,
                            const float* __restrict__ top5,
                            const int* __restrict__ numneg,
                            float* __restrict__ rsum,
                            unsigned int* __restrict__ nrp) {
    int p = blockIdx.x * blockDim.x + threadIdx.x;
    float c = 0.0f;
    unsigned int valid = 0;
    if (p < P_PAIRS) {
        int b = pb[p];
        int t = pt[p];
        float pos = scores[(size_t)b * NT + t];
        #pragma unroll
        for (int k = 0; k < 5; ++k) {
            float tn = top5[b * 5 + k];
            float contrib = MARGIN - (pos - tn);
            c += contrib > 0.0f ? contrib : 0.0f;
        }
        int nn = numneg[b];
        valid = (unsigned int)(nn < 5 ? nn : 5);
    }
    #pragma unroll
    for (int off = 32; off >= 1; off >>= 1) {
        c     += __shfl_xor(c, off);
        valid += __shfl_xor(valid, off);
    }
    if ((threadIdx.x & 63) == 0) {
        atomicAdd(rsum, c);
        atomicAdd(nrp, valid);
    }
}

__global__ void finalize_kernel(const float* __restrict__ sq_partials,
                                const float* __restrict__ rsum,
                                const unsigned int* __restrict__ nrp,
                                float* __restrict__ out) {
    float s = 0.0f;
    for (int i = threadIdx.x; i < NB; i += blockDim.x) s += sq_partials[i];
    #pragma unroll
    for (int off = 32; off >= 1; off >>= 1) s += __shfl_xor(s, off);

    __shared__ float smem[8];
    int wave = threadIdx.x >> 6;
    int lane = threadIdx.x & 63;
    if (lane == 0) smem[wave] = s;
    __syncthreads();
    if (threadIdx.x == 0) {
        float tot = 0.0f;
        int nwaves = blockDim.x >> 6;
        for (int w = 0; w < nwaves; ++w) tot += smem[w];
        float loss = 0.5f * tot / (float)((double)NB * (double)NT);
        unsigned int n = *nrp;
        if (n > 0) loss += RANK_W * (*rsum) / (float)n;
        out[0] = loss;
    }
}

extern "C" void kernel_launch(void* const* d_in, const int* in_sizes, int n_in,
                              void* d_out, int out_size, void* d_ws, size_t ws_size,
                              hipStream_t stream) {
    const float* scores = (const float*)d_in[0];
    const int*   pb     = (const int*)d_in[1];
    const int*   pt     = (const int*)d_in[2];
    float*       out    = (float*)d_out;

    char* ws = (char*)d_ws;
    unsigned int* mask        = (unsigned int*)ws;
    float*        rsum        = (float*)(ws + 2560000);
    unsigned int* nrp         = (unsigned int*)(ws + 2560004);
    float*        sq_partials = (float*)(ws + 2560016);
    float*        top5        = (float*)(ws + 2640016);
    int*          numneg      = (int*)(ws + 3040016);

    // zero bitmask + accumulators (sq_partials/top5/numneg are fully overwritten)
    hipMemsetAsync(ws, 0, 2560016, stream);

    scatter_labels_kernel<<<(P_PAIRS + 255) / 256, 256, 0, stream>>>(pb, pt, mask);
    row_kernel<<<NB / 4, 256, 0, stream>>>(scores, mask, sq_partials, top5, numneg);
    pair_kernel<<<(P_PAIRS + 255) / 256, 256, 0, stream>>>(scores, pb, pt, top5, numneg, rsum, nrp);
    finalize_kernel<<<1, 256, 0, stream>>>(sq_partials, rsum, nrp, out);
}

// Round 2
// 83.843 us; speedup vs baseline: 1.0069x; 1.0069x over previous
//
#include <hip/hip_runtime.h>
#include <cstdint>
#include <cstddef>

#define NB 20000
#define NT 1000
#define P_PAIRS 50000
#define MARGIN 2.0f
#define RANK_W 0.3f
#define NEG_SENT -1e9f

// ---------------- workspace layout (bytes) ----------------
// [0,          2560000)  label bitmask: uint32 [NB][32]
// [2560000,    2560004)  float  ranking_sum accumulator
// [2560004,    2560008)  uint   num_ranking_pairs accumulator
// [2560016,    2640016)  float  sq_partials[NB]        (fully overwritten, no zero needed)
// [2640016,    3040016)  float  top5[NB][5]
// [3040016,    3120016)  int    numneg[NB]
// zero range: [0, 2560016) = 160001 uint4

#define ZERO_U4 160001

__global__ void zero_ws_kernel(uint4* __restrict__ ws) {
    int i = blockIdx.x * blockDim.x + threadIdx.x;
    if (i < ZERO_U4) ws[i] = make_uint4(0u, 0u, 0u, 0u);
}

__global__ void scatter_labels_kernel(const int* __restrict__ pb,
                                      const int* __restrict__ pt,
                                      unsigned int* __restrict__ mask) {
    int p = blockIdx.x * blockDim.x + threadIdx.x;
    if (p >= P_PAIRS) return;
    int b = pb[p];
    int t = pt[p];
    atomicOr(&mask[b * 32 + (t >> 5)], 1u << (t & 31));
}

// One wave (64 lanes) per row. 4 waves / block.
__global__ void row_kernel(const float* __restrict__ scores,
                           const unsigned int* __restrict__ mask,
                           float* __restrict__ sq_partials,
                           float* __restrict__ top5,
                           int* __restrict__ numneg) {
    const int wave = threadIdx.x >> 6;
    const int lane = threadIdx.x & 63;
    const int row  = blockIdx.x * 4 + wave;
    if (row >= NB) return;

    const float4* rowp = reinterpret_cast<const float4*>(scores + (size_t)row * NT);
    const unsigned int* mrow = mask + row * 32;

    float t0 = NEG_SENT, t1 = NEG_SENT, t2 = NEG_SENT, t3 = NEG_SENT, t4 = NEG_SENT;
    float sq = 0.0f;
    int pcount = 0;

    for (int i = lane; i < NT / 4; i += 64) {
        float4 v = rowp[i];
        int e = i * 4;
        unsigned int bits = (mrow[e >> 5] >> (e & 31)) & 0xFu;
        float vv[4] = {v.x, v.y, v.z, v.w};
        #pragma unroll
        for (int j = 0; j < 4; ++j) {
            float x = vv[j];
            float s = 1.0f / (1.0f + __expf(-x));
            int lab = (bits >> j) & 1;
            float d = (float)lab - s;
            sq += d * d;
            if (lab) {
                pcount++;
            } else if (x > t4) {
                if (x > t0)      { t4 = t3; t3 = t2; t2 = t1; t1 = t0; t0 = x; }
                else if (x > t1) { t4 = t3; t3 = t2; t2 = t1; t1 = x; }
                else if (x > t2) { t4 = t3; t3 = t2; t2 = x; }
                else if (x > t3) { t4 = t3; t3 = x; }
                else             { t4 = x; }
            }
        }
    }

    // wave-reduce sq sum and positive count
    #pragma unroll
    for (int off = 32; off >= 1; off >>= 1) {
        sq     += __shfl_xor(sq, off);
        pcount += __shfl_xor(pcount, off);
    }

    // wave-merge top-5: 5 rounds of argmax + pop (lowest tied lane pops)
    float t[5] = {t0, t1, t2, t3, t4};
    float r[5];
    #pragma unroll
    for (int k = 0; k < 5; ++k) {
        float v = t[0];
        float m = v;
        #pragma unroll
        for (int off = 32; off >= 1; off >>= 1) m = fmaxf(m, __shfl_xor(m, off));
        unsigned long long ball = __ballot(v == m);
        int owner = __ffsll(ball) - 1;
        if (lane == owner) { t[0] = t[1]; t[1] = t[2]; t[2] = t[3]; t[3] = t[4]; t[4] = NEG_SENT; }
        r[k] = m;
    }

    if (lane == 0) {
        sq_partials[row] = sq;
        #pragma unroll
        for (int k = 0; k < 5; ++k) top5[row * 5 + k] = r[k];
        numneg[row] = NT - pcount;
    }
}

__global__ void pair_kernel(const float* __restrict__ scores,
                            const int* __restrict__ pb,
                            const int* __restrict__ pt,
                            const float* __restrict__ top5,
                            const int* __restrict__ numneg,
                            float* __restrict__ rsum,
                            unsigned int* __restrict__ nrp) {
    int p = blockIdx.x * blockDim.x + threadIdx.x;
    float c = 0.0f;
    unsigned int valid = 0;
    if (p < P_PAIRS) {
        int b = pb[p];
        int t = pt[p];
        float pos = scores[(size_t)b * NT + t];
        #pragma unroll
        for (int k = 0; k < 5; ++k) {
            float tn = top5[b * 5 + k];
            float contrib = MARGIN - (pos - tn);
            c += contrib > 0.0f ? contrib : 0.0f;
        }
        int nn = numneg[b];
        valid = (unsigned int)(nn < 5 ? nn : 5);
    }
    #pragma unroll
    for (int off = 32; off >= 1; off >>= 1) {
        c     += __shfl_xor(c, off);
        valid += __shfl_xor(valid, off);
    }
    if ((threadIdx.x & 63) == 0) {
        atomicAdd(rsum, c);
        atomicAdd(nrp, valid);
    }
}

__global__ void finalize_kernel(const float* __restrict__ sq_partials,
                                const float* __restrict__ rsum,
                                const unsigned int* __restrict__ nrp,
                                float* __restrict__ out) {
    float s = 0.0f;
    for (int i = threadIdx.x; i < NB; i += blockDim.x) s += sq_partials[i];
    #pragma unroll
    for (int off = 32; off >= 1; off >>= 1) s += __shfl_xor(s, off);

    __shared__ float smem[8];
    int wave = threadIdx.x >> 6;
    int lane = threadIdx.x & 63;
    if (lane == 0) smem[wave] = s;
    __syncthreads();
    if (threadIdx.x == 0) {
        float tot = 0.0f;
        int nwaves = blockDim.x >> 6;
        for (int w = 0; w < nwaves; ++w) tot += smem[w];
        float loss = 0.5f * tot / (float)((double)NB * (double)NT);
        unsigned int n = *nrp;
        if (n > 0) loss += RANK_W * (*rsum) / (float)n;
        out[0] = loss;
    }
}

extern "C" void kernel_launch(void* const* d_in, const int* in_sizes, int n_in,
                              void* d_out, int out_size, void* d_ws, size_t ws_size,
                              hipStream_t stream) {
    const float* scores = (const float*)d_in[0];
    const int*   pb     = (const int*)d_in[1];
    const int*   pt     = (const int*)d_in[2];
    float*       out    = (float*)d_out;

    char* ws = (char*)d_ws;
    unsigned int* mask        = (unsigned int*)ws;
    float*        rsum        = (float*)(ws + 2560000);
    unsigned int* nrp         = (unsigned int*)(ws + 2560004);
    float*        sq_partials = (float*)(ws + 2560016);
    float*        top5        = (float*)(ws + 2640016);
    int*          numneg      = (int*)(ws + 3040016);

    // zero bitmask + accumulators with our own kernel (rocclr fill was 47us @ 55GB/s)
    zero_ws_kernel<<<(ZERO_U4 + 255) / 256, 256, 0, stream>>>((uint4*)ws);

    scatter_labels_kernel<<<(P_PAIRS + 255) / 256, 256, 0, stream>>>(pb, pt, mask);
    row_kernel<<<NB / 4, 256, 0, stream>>>(scores, mask, sq_partials, top5, numneg);
    pair_kernel<<<(P_PAIRS + 255) / 256, 256, 0, stream>>>(scores, pb, pt, top5, numneg, rsum, nrp);
    finalize_kernel<<<1, 256, 0, stream>>>(sq_partials, rsum, nrp, out);
}